// Round 3
// baseline (159.481 us; speedup 1.0000x reference)
//
#include <hip/hip_runtime.h>
#include <hip/hip_cooperative_groups.h>
#include <math.h>

namespace cg = cooperative_groups;

// ---------------------------------------------------------------------------
// Problem: B=32, L=1024, C=34, PATCH=16, d=256, E=8, pred=96.
// Algebraic reductions (verified R1-R7):
//   * final [:, :, :1] slice -> only channel n=0 per batch (series x[b,:,2])
//   * flat[:, :1024] truncation -> only patches p=0..3 contribute
//
// FLOOR DECOMPOSITION (R10 post-mortem): kernel WORK is ~10us total
// (counters: every kernel < 40us, L2-resident traffic, 1280 ds_reads ~2.5k
// clk, FMA floor ~1us).  dur_us=98.8 ~= 2x41us workspace re-poison fills
// (268MB @ 82% HBM peak, visible as fillBufferAligned in every round's
// top-5) + ~10us kernels + launch gaps.  Structural kernel changes move
// only the launch-gap component (-10, -2 across R9/R10).
//
// R11: direct floor test = SINGLE cooperative launch (last controllable
// structure).  One kernel: phase 1 = fused stats/proj/router/expert
// (R10 body, absmax 1.2e-7), grid.sync() (guide-blessed cross-XCD
// coherent), phase 2 = head.  Fallback on launch error: same kernel as
// two phase-flagged launches == R10 structure.
// Decision rule: >=97us => harness-fixed floor, declare and stop.
// ---------------------------------------------------------------------------

#define NB 32
#define LSEQ 1024
#define CCH 34
#define NP 4
#define DMODEL 256
#define NEXP 8
#define PRED 96
#define DT 64                                   // d-tile width
#define NPART NEXP                              // 8 partial buffers (per e)

#define STATS_FLOATS (NB * 2)                   // 64

#define PH_BOTH   0
#define PH_EXPERT 1
#define PH_HEAD   2

// ---------------------------------------------------------------------------
// Unified kernel.  grid = 256, block = 256, 1 block/CU (74 KB LDS).
// Expert phase: bid -> (e = bid&7 [XCD-local slice], b = bid>>3).
// Head   phase: bid -> (b = bid>>3, kq = bid&7).
// ---------------------------------------------------------------------------
__global__ __launch_bounds__(256) void k_all(
    const float* __restrict__ x,
    const float* __restrict__ W_proj, const float* __restrict__ b_proj,
    const float* __restrict__ W_router, const float* __restrict__ b_router,
    const float* __restrict__ W_experts, const float* __restrict__ b_experts,
    const float* __restrict__ W_head, const float* __restrict__ b_head,
    float* __restrict__ flat_part, float* __restrict__ stats_ws,
    float* __restrict__ out, int phase)
{
    const int bid = blockIdx.x;
    const int tid = threadIdx.x;

    __shared__ float wtT[DT][DMODEL + 1];          // 65.8 KB transposed tile
    __shared__ __align__(16) float xn[LSEQ];       // 4 KB (aliased in head)
    __shared__ float xp_s[NP * DMODEL];
    __shared__ float red[8];
    __shared__ float lg[32];
    __shared__ float g_s[NP];
    __shared__ float mean_s, rstd_s;

    if (phase != PH_HEAD) {
        const int e = bid & 7;        // low bits -> XCD id -> L2-local slice
        const int b = bid >> 3;

        // ---- issue series loads FIRST (long latency), then tile-0 W loads
        float v[4];
        #pragma unroll
        for (int i = 0; i < 4; ++i)
            v[i] = x[(size_t)(b * LSEQ + tid + 256 * i) * CCH + 2];

        // W tile mapping: c4 = float4 chunk of d, hb+16i = h row.
        const int c4 = tid & 15;
        const int hb = tid >> 4;
        const float* wsrc = W_experts + ((size_t)e << 16);
        float4 wreg[16];
        #pragma unroll
        for (int i = 0; i < 16; ++i)
            wreg[i] = *(const float4*)(wsrc + (size_t)(hb + 16 * i) * DMODEL + 4 * c4);

        // ---- stats over the 1024-length series
        {
            float s = 0.f, sq = 0.f;
            #pragma unroll
            for (int i = 0; i < 4; ++i) { s += v[i]; sq += v[i] * v[i]; }
            #pragma unroll
            for (int off = 32; off > 0; off >>= 1) {
                s  += __shfl_down(s,  off);
                sq += __shfl_down(sq, off);
            }
            const int wave = tid >> 6;
            if ((tid & 63) == 0) { red[wave * 2] = s; red[wave * 2 + 1] = sq; }
            __syncthreads();
            if (tid == 0) {
                const float S = red[0] + red[2] + red[4] + red[6];
                const float Q = red[1] + red[3] + red[5] + red[7];
                const float mean = S * (1.0f / LSEQ);
                const float var  = Q * (1.0f / LSEQ) - mean * mean;
                const float stdv = sqrtf(var + 1e-5f);
                mean_s = mean;
                rstd_s = 1.0f / stdv;
                if (e == 0) {                 // one writer per batch
                    stats_ws[b * 2]     = mean;
                    stats_ws[b * 2 + 1] = stdv;
                }
            }
            __syncthreads();
            const float mean = mean_s, rstd = rstd_s;
            #pragma unroll
            for (int i = 0; i < 4; ++i)
                xn[tid + 256 * i] = (v[i] - mean) * rstd;
            __syncthreads();
        }

        // ---- patch projection: xp[p][h], thread h
        {
            const int h = tid;
            float wrow[16];
            #pragma unroll
            for (int j = 0; j < 16; ++j) wrow[j] = W_proj[h * 16 + j];
            const float bp = b_proj[h];
            #pragma unroll
            for (int p = 0; p < NP; ++p) {
                float acc = bp;
                #pragma unroll
                for (int j = 0; j < 16; ++j) acc += xn[p * 16 + j] * wrow[j];
                xp_s[p * DMODEL + h] = acc;
            }
        }
        __syncthreads();

        // ---- router logits, parallel: 8 lanes per (p,e') pair
        {
            const int pe = tid >> 3;
            const int sl = tid & 7;
            const int p  = pe >> 3;
            const int er = pe & 7;
            float acc = 0.f;
            #pragma unroll 8
            for (int j = 0; j < 32; ++j) {
                const int hh = sl + 8 * j;
                acc += xp_s[p * DMODEL + hh] * W_router[er * DMODEL + hh];
            }
            acc += __shfl_xor(acc, 4);
            acc += __shfl_xor(acc, 2);
            acc += __shfl_xor(acc, 1);
            if (sl == 0) lg[pe] = acc + b_router[er];
        }
        __syncthreads();

        // ---- softmax over 8 experts; keep only this block's gate g[p]
        if (tid < NP) {
            const int p = tid;
            float m = -1e30f;
            #pragma unroll
            for (int k = 0; k < NEXP; ++k) m = fmaxf(m, lg[p * 8 + k]);
            float ex[NEXP];
            float sum = 0.f;
            #pragma unroll
            for (int k = 0; k < NEXP; ++k) { ex[k] = expf(lg[p * 8 + k] - m); sum += ex[k]; }
            g_s[p] = ex[e] / sum;
        }
        // g_s visibility covered by the tile-loop barriers below

        // ---- expert matvec: 4 d-tiles, LDS transpose, reg-prefetch next
        float acc0 = 0.f, acc1 = 0.f, acc2 = 0.f, acc3 = 0.f;
        for (int t = 0; t < 4; ++t) {
            __syncthreads();
            #pragma unroll
            for (int i = 0; i < 16; ++i) {
                const int h = hb + 16 * i;
                wtT[4 * c4 + 0][h] = wreg[i].x;
                wtT[4 * c4 + 1][h] = wreg[i].y;
                wtT[4 * c4 + 2][h] = wreg[i].z;
                wtT[4 * c4 + 3][h] = wreg[i].w;
            }
            __syncthreads();
            if (t < 3) {
                #pragma unroll
                for (int i = 0; i < 16; ++i)
                    wreg[i] = *(const float4*)(wsrc + (size_t)(hb + 16 * i) * DMODEL
                                               + (t + 1) * DT + 4 * c4);
            }
            const float* xpp = xp_s + t * DT;
            #pragma unroll 8
            for (int c = 0; c < DT; ++c) {
                const float wv = wtT[c][tid];
                acc0 += xpp[c]       * wv;
                acc1 += xpp[256 + c] * wv;
                acc2 += xpp[512 + c] * wv;
                acc3 += xpp[768 + c] * wv;
            }
        }

        // ---- gated write of this expert's partial (coalesced, disjoint)
        const float bias = b_experts[(e << 8) + tid];
        const size_t base = ((size_t)(e * NB + b) << 10) + tid;
        flat_part[base]         = g_s[0] * (acc0 + bias);
        flat_part[base + 256]   = g_s[1] * (acc1 + bias);
        flat_part[base + 512]   = g_s[2] * (acc2 + bias);
        flat_part[base + 768]   = g_s[3] * (acc3 + bias);
    }

    if (phase == PH_BOTH) {
        __threadfence();              // device-scope release of flat/stats
        cg::this_grid().sync();       // cross-XCD coherent handoff
    }

    if (phase != PH_EXPERT) {
        const int b  = bid >> 3;
        const int kq = bid & 7;
        float4* f4s = (float4*)xn;    // reuse 4 KB LDS (16B-aligned)

        const float mean = stats_ws[b * 2];
        const float stdv = stats_ws[b * 2 + 1];

        // stage: f[l] = (sum_e part[e][b][l]) * std + mean  (fixed e-order)
        {
            float4 acc = make_float4(0.f, 0.f, 0.f, 0.f);
            #pragma unroll
            for (int i = 0; i < NPART; ++i) {
                const float4 t =
                    ((const float4*)(flat_part + (((size_t)i * NB + b) << 10)))[tid];
                acc.x += t.x; acc.y += t.y; acc.z += t.z; acc.w += t.w;
            }
            acc.x = acc.x * stdv + mean;
            acc.y = acc.y * stdv + mean;
            acc.z = acc.z * stdv + mean;
            acc.w = acc.w * stdv + mean;
            f4s[tid] = acc;
        }
        __syncthreads();

        const int lane = tid & 63;
        const int w    = tid >> 6;
        float4 fr[4];
        #pragma unroll
        for (int c = 0; c < 4; ++c) fr[c] = f4s[lane + 64 * c];

        #pragma unroll
        for (int i = 0; i < 3; ++i) {
            const int k = kq * 12 + w + 4 * i;
            const float4* wr = (const float4*)(W_head + (size_t)k * LSEQ);
            float a = 0.f;
            #pragma unroll
            for (int c = 0; c < 4; ++c) {
                const float4 t = wr[lane + 64 * c];
                a += t.x * fr[c].x + t.y * fr[c].y + t.z * fr[c].z + t.w * fr[c].w;
            }
            #pragma unroll
            for (int off = 32; off > 0; off >>= 1)
                a += __shfl_xor(a, off);
            if (lane == 0)
                out[(size_t)b * PRED + k] = b_head[k] + a;
        }
    }
}

// ---------------------------------------------------------------------------
extern "C" void kernel_launch(void* const* d_in, const int* in_sizes, int n_in,
                              void* d_out, int out_size, void* d_ws, size_t ws_size,
                              hipStream_t stream)
{
    const float* x         = (const float*)d_in[0];
    const float* W_proj    = (const float*)d_in[4];
    const float* b_proj    = (const float*)d_in[5];
    const float* W_router  = (const float*)d_in[6];
    const float* b_router  = (const float*)d_in[7];
    const float* W_experts = (const float*)d_in[8];
    const float* b_experts = (const float*)d_in[9];
    const float* W_head    = (const float*)d_in[10];
    const float* b_head    = (const float*)d_in[11];
    float* out = (float*)d_out;
    float* ws  = (float*)d_ws;

    float* stats_ws  = ws;
    float* flat_part = ws + STATS_FLOATS;   // 8 x NB x LSEQ floats

    int phase = PH_BOTH;
    void* args[] = {
        (void*)&x, (void*)&W_proj, (void*)&b_proj, (void*)&W_router,
        (void*)&b_router, (void*)&W_experts, (void*)&b_experts,
        (void*)&W_head, (void*)&b_head, (void*)&flat_part,
        (void*)&stats_ws, (void*)&out, (void*)&phase
    };

    hipError_t err = hipLaunchCooperativeKernel(
        (const void*)k_all, dim3(256), dim3(256), args, 0, stream);

    if (err != hipSuccess) {
        // cooperative launch not available (e.g. under graph capture):
        // fall back to the proven R10 two-launch structure.
        (void)hipGetLastError();
        k_all<<<256, 256, 0, stream>>>(x, W_proj, b_proj, W_router, b_router,
                                       W_experts, b_experts, W_head, b_head,
                                       flat_part, stats_ws, out, PH_EXPERT);
        k_all<<<256, 256, 0, stream>>>(x, W_proj, b_proj, W_router, b_router,
                                       W_experts, b_experts, W_head, b_head,
                                       flat_part, stats_ws, out, PH_HEAD);
    }
}

// Round 4
// 113.920 us; speedup vs baseline: 1.3999x; 1.3999x over previous
//
#include <hip/hip_runtime.h>
#include <math.h>

// ---------------------------------------------------------------------------
// Problem: B=32, L=1024, C=34, PATCH=16, d=256, E=8, pred=96.
// Algebraic reductions (verified R1-R7):
//   * final [:, :, :1] slice -> only channel n=0 per batch (series x[b,:,2])
//   * flat[:, :1024] truncation -> only patches p=0..3 contribute
//
// R11 post-mortem (cooperative, 159us, REVERTED) exposed the real profile:
//   expert phase ~60us with VALUBusy 5%, BW 5%, Occ 10.5%, FETCH 21.9MB.
//   => latency-bound at 1 wave/SIMD + x-gather touches 1 line/element and
//      is re-fetched by every XCD (e=bid&7 put all 32 series on all XCDs).
//
// R12: revert to two plain launches; rebuild k_fused:
//   * block=1024 (16 waves = 4 waves/SIMD; R9-proven latency-hiding regime)
//   * x loaded as coalesced float4 stream of x[b] (139KB) + in-reg channel-2
//     extract; grid mapped b=bid&31 so XCD=b%8: each series streamed by ONE
//     XCD (x fetch 33MB->4.4MB), W (2MB) L2-resident per XCD.
//   * W tile kept ROW-major in LDS wtS[256][68] (odd float4 stride ->
//     conflict-free b128 store AND read); no transpose; 4x fewer LDS instrs.
//   k_head: R10 verbatim (proven, absmax 1.2e-7).
// ---------------------------------------------------------------------------

#define NB 32
#define LSEQ 1024
#define CCH 34
#define NP 4
#define DMODEL 256
#define NEXP 8
#define PRED 96
#define DT 64                                   // d-tile width
#define NPART NEXP                              // 8 partial buffers (per e)

#define STATS_FLOATS (NB * 2)                   // 64
#define XCHUNKS ((LSEQ * CCH) / 4)              // 8704 float4 per batch row

// ---------------------------------------------------------------------------
// Kernel A: fused stats + patch-proj + router + expert matvec.
// grid = 256: bid -> (e = bid>>5, b = bid&31)  [XCD = bid%8 = b%8]
// block = 1024 (16 waves, 4 waves/SIMD).  LDS ~76 KB -> 1 block/CU.
// ---------------------------------------------------------------------------
__global__ __launch_bounds__(1024) void k_fused(
    const float* __restrict__ x,
    const float* __restrict__ W_proj, const float* __restrict__ b_proj,
    const float* __restrict__ W_router, const float* __restrict__ b_router,
    const float* __restrict__ W_experts, const float* __restrict__ b_experts,
    float* __restrict__ flat_part, float* __restrict__ stats_ws)
{
    const int bid = blockIdx.x;
    const int e   = bid >> 5;
    const int b   = bid & 31;         // low bits -> XCD id = b%8
    const int tid = threadIdx.x;

    __shared__ __align__(16) float wtS[DMODEL][DT + 4];  // [h][d], 68 KB
    __shared__ __align__(16) float xn[LSEQ];             // 4 KB
    __shared__ __align__(16) float xp_s[NP * DMODEL];    // 4 KB
    __shared__ float red[32];
    __shared__ float lg[32];
    __shared__ float g_s[NP];
    __shared__ float mean_s, rstd_s;

    // ---- coalesced stream of x[b] (all 34 channels) + channel-2 extract.
    // chan-2 element l sits at float offset 34l+2; chunk k covers 4k..4k+3;
    // l0 = ceil((4k-2)/34) = (4k+31)/34; hit iff 34*l0+2 <= 4k+3.
    {
        const float4* xr = (const float4*)(x + (size_t)b * (LSEQ * CCH));
        #pragma unroll
        for (int j = 0; j < 9; ++j) {
            const int k = tid + (j << 10);
            if (k < XCHUNKS) {
                const float4 f = xr[k];
                const int base = 4 * k;
                const int l0   = (base + 31) / 34;
                const int off  = 34 * l0 + 2 - base;
                if (off < 4 && l0 < LSEQ) {
                    const float val = (off == 0) ? f.x : (off == 1) ? f.y
                                    : (off == 2) ? f.z : f.w;
                    xn[l0] = val;
                }
            }
        }
    }

    // ---- prefetch W tile 0 while the stream drains (register-only)
    const int c4 = tid & 15;          // float4 chunk within 64-d tile
    const int hb = tid >> 4;          // row base 0..63
    const float* wsrc = W_experts + ((size_t)e << 16);
    float4 wreg[4];
    #pragma unroll
    for (int i = 0; i < 4; ++i)
        wreg[i] = *(const float4*)(wsrc + (size_t)(hb + 64 * i) * DMODEL + 4 * c4);

    __syncthreads();

    // ---- stats: 1 element/thread, 16-wave reduce
    {
        const float v = xn[tid];
        float s = v, sq = v * v;
        #pragma unroll
        for (int off = 32; off > 0; off >>= 1) {
            s  += __shfl_down(s,  off);
            sq += __shfl_down(sq, off);
        }
        const int wave = tid >> 6;
        if ((tid & 63) == 0) { red[wave * 2] = s; red[wave * 2 + 1] = sq; }
        __syncthreads();
        if (tid == 0) {
            float S = 0.f, Q = 0.f;
            #pragma unroll
            for (int w = 0; w < 16; ++w) { S += red[2 * w]; Q += red[2 * w + 1]; }
            const float mean = S * (1.0f / LSEQ);
            const float var  = Q * (1.0f / LSEQ) - mean * mean;
            const float stdv = sqrtf(var + 1e-5f);
            mean_s = mean;
            rstd_s = 1.0f / stdv;
            if (e == 0) {                 // one writer per batch
                stats_ws[b * 2]     = mean;
                stats_ws[b * 2 + 1] = stdv;
            }
        }
        __syncthreads();
        xn[tid] = (v - mean_s) * rstd_s;
        __syncthreads();
    }

    const int p = tid >> 8;           // patch 0..3
    const int h = tid & 255;          // output dim 0..255

    // ---- patch projection: xp[p][h] (only l=0..63 used: 4 patches)
    {
        const float* wp = W_proj + h * 16;
        float acc = b_proj[h];
        #pragma unroll
        for (int j = 0; j < 16; ++j) acc += xn[p * 16 + j] * wp[j];
        xp_s[p * DMODEL + h] = acc;
    }
    __syncthreads();

    // ---- router logits, parallel: 8 lanes per (p,e') pair (tid<256)
    if (tid < 256) {
        const int pe = tid >> 3;
        const int sl = tid & 7;
        const int pp = pe >> 3;
        const int er = pe & 7;
        float acc = 0.f;
        #pragma unroll 8
        for (int j = 0; j < 32; ++j) {
            const int hh = sl + 8 * j;
            acc += xp_s[pp * DMODEL + hh] * W_router[er * DMODEL + hh];
        }
        acc += __shfl_xor(acc, 4);
        acc += __shfl_xor(acc, 2);
        acc += __shfl_xor(acc, 1);
        if (sl == 0) lg[pe] = acc + b_router[er];
    }
    __syncthreads();

    // ---- softmax over 8 experts; keep only this block's gate g[p]
    if (tid < NP) {
        const int pp = tid;
        float m = -1e30f;
        #pragma unroll
        for (int k = 0; k < NEXP; ++k) m = fmaxf(m, lg[pp * 8 + k]);
        float ex[NEXP];
        float sum = 0.f;
        #pragma unroll
        for (int k = 0; k < NEXP; ++k) { ex[k] = expf(lg[pp * 8 + k] - m); sum += ex[k]; }
        g_s[pp] = ex[e] / sum;
    }
    // g_s visibility covered by the tile-loop barriers below

    // ---- expert matvec: 4 d-tiles; row-major LDS tile, b128 both sides
    float acc = 0.f;
    for (int t = 0; t < 4; ++t) {
        __syncthreads();   // protect wtS from overwrite while prior reads run
        #pragma unroll
        for (int i = 0; i < 4; ++i)
            ((float4*)&wtS[hb + 64 * i][0])[c4] = wreg[i];
        __syncthreads();
        if (t < 3) {
            #pragma unroll
            for (int i = 0; i < 4; ++i)
                wreg[i] = *(const float4*)(wsrc + (size_t)(hb + 64 * i) * DMODEL
                                           + (t + 1) * DT + 4 * c4);
        }
        const float4* wrow = (const float4*)&wtS[h][0];
        const float4* xpp  = (const float4*)&xp_s[p * DMODEL + t * DT];
        #pragma unroll
        for (int q = 0; q < 16; ++q) {
            const float4 wv = wrow[q];
            const float4 xv = xpp[q];
            acc += wv.x * xv.x + wv.y * xv.y + wv.z * xv.z + wv.w * xv.w;
        }
    }

    // ---- gated write of this expert's partial (coalesced, disjoint)
    const float bias = b_experts[(e << 8) + h];
    flat_part[(((size_t)(e * NB + b)) << 10) + (p << 8) + h] = g_s[p] * (acc + bias);
}

// ---------------------------------------------------------------------------
// Kernel B: sum 8 partials, un-normalize, head matvec.  (R10 verbatim)
// grid = 256: bid -> (b = bid>>3, kq = bid&7); block = 256 (4 waves).
// ---------------------------------------------------------------------------
__global__ __launch_bounds__(256) void k_head(
    const float* __restrict__ flat_part, const float* __restrict__ stats_ws,
    const float* __restrict__ W_head, const float* __restrict__ b_head,
    float* __restrict__ out)
{
    const int b   = blockIdx.x >> 3;
    const int kq  = blockIdx.x & 7;
    const int tid = threadIdx.x;
    __shared__ float4 f4s[DMODEL];   // 1024 floats

    const float mean = stats_ws[b * 2];
    const float stdv = stats_ws[b * 2 + 1];

    // stage: f[l] = (sum_e part[e][b][l]) * std + mean  (fixed e-order)
    {
        float4 acc = make_float4(0.f, 0.f, 0.f, 0.f);
        #pragma unroll
        for (int i = 0; i < NPART; ++i) {
            const float4 t =
                ((const float4*)(flat_part + (((size_t)i * NB + b) << 10)))[tid];
            acc.x += t.x; acc.y += t.y; acc.z += t.z; acc.w += t.w;
        }
        acc.x = acc.x * stdv + mean;
        acc.y = acc.y * stdv + mean;
        acc.z = acc.z * stdv + mean;
        acc.w = acc.w * stdv + mean;
        f4s[tid] = acc;
    }
    __syncthreads();

    const int lane = tid & 63;
    const int w    = tid >> 6;
    float4 fr[4];
    #pragma unroll
    for (int c = 0; c < 4; ++c) fr[c] = f4s[lane + 64 * c];

    #pragma unroll
    for (int i = 0; i < 3; ++i) {
        const int k = kq * 12 + w + 4 * i;
        const float4* wr = (const float4*)(W_head + (size_t)k * LSEQ);
        float a = 0.f;
        #pragma unroll
        for (int c = 0; c < 4; ++c) {
            const float4 t = wr[lane + 64 * c];
            a += t.x * fr[c].x + t.y * fr[c].y + t.z * fr[c].z + t.w * fr[c].w;
        }
        #pragma unroll
        for (int off = 32; off > 0; off >>= 1)
            a += __shfl_xor(a, off);
        if (lane == 0)
            out[(size_t)b * PRED + k] = b_head[k] + a;
    }
}

// ---------------------------------------------------------------------------
extern "C" void kernel_launch(void* const* d_in, const int* in_sizes, int n_in,
                              void* d_out, int out_size, void* d_ws, size_t ws_size,
                              hipStream_t stream)
{
    const float* x         = (const float*)d_in[0];
    const float* W_proj    = (const float*)d_in[4];
    const float* b_proj    = (const float*)d_in[5];
    const float* W_router  = (const float*)d_in[6];
    const float* b_router  = (const float*)d_in[7];
    const float* W_experts = (const float*)d_in[8];
    const float* b_experts = (const float*)d_in[9];
    const float* W_head    = (const float*)d_in[10];
    const float* b_head    = (const float*)d_in[11];
    float* out = (float*)d_out;
    float* ws  = (float*)d_ws;

    float* stats_ws  = ws;
    float* flat_part = ws + STATS_FLOATS;   // 8 x NB x LSEQ floats

    k_fused<<<256, 1024, 0, stream>>>(x, W_proj, b_proj, W_router, b_router,
                                      W_experts, b_experts, flat_part, stats_ws);
    k_head<<<256, 256, 0, stream>>>(flat_part, stats_ws, W_head, b_head, out);
}

// Round 5
// 96.608 us; speedup vs baseline: 1.6508x; 1.1792x over previous
//
#include <hip/hip_runtime.h>
#include <math.h>

// ---------------------------------------------------------------------------
// Problem: B=32, L=1024, C=34, PATCH=16, d=256, E=8, pred=96.
// Algebraic reductions (verified R1-R7):
//   * final [:, :, :1] slice -> only channel n=0 per batch (series x[b,:,2])
//   * flat[:, :1024] truncation -> only patches p=0..3 contribute
//
// LEDGER: R10 (fused 2-kernel, 256x256, LDS transpose) = 98.8us BEST.
//   R11 cooperative = 159.5 (REVERTED; grid.sync + eager fallback toxic).
//   R12 block-1024 rebuild = 113.9 (REVERTED; 1 blk/CU serialization +
//   8-way b128 read conflicts in row-major tile).
//   Fixed harness floor ~85-90us (workspace re-poison fills @41us, graph
//   overhead); controllable slice = kernels + gaps ~14-17us at R10.
//
// R13 = R10 + two surgical deltas (everything else byte-identical):
//   1) d-split: grid 512 = (b,e,dh); 74KB LDS x2 = 148.5 <= 160KB ->
//      2 blocks/CU, 2 waves/SIMD, halved serial matvec depth.  16 partial
//      buffers part=(e<<1)|dh summed by R9's proven k_head.
//   2) XCD grouping {8b x 4e}: bid%8 = (b&3)*2+(e&1) -> per-XCD unique
//      x = 1.1MB (was 4.45), FETCH ~21.9 -> ~17MB.
// Decision rule (pre-committed): dur >= 97us -> declare harness floor.
// ---------------------------------------------------------------------------

#define NB 32
#define LSEQ 1024
#define CCH 34
#define NP 4
#define DMODEL 256
#define NEXP 8
#define PRED 96
#define DT 64                                   // d-tile width
#define NPART (2 * NEXP)                        // 16 partials (e, dh)

#define STATS_FLOATS (NB * 2)                   // 64

// ---------------------------------------------------------------------------
// Kernel A: fused stats + patch-proj + router + half-d expert matvec.
// grid = 512: bid -> (b, e, dh) via XCD-aware encode (see launch);
// block = 256.  LDS ~74 KB -> 2 blocks/CU (2 waves/SIMD).
// ---------------------------------------------------------------------------
__global__ __launch_bounds__(256, 2) void k_fused(
    const float* __restrict__ x,
    const float* __restrict__ W_proj, const float* __restrict__ b_proj,
    const float* __restrict__ W_router, const float* __restrict__ b_router,
    const float* __restrict__ W_experts, const float* __restrict__ b_experts,
    float* __restrict__ flat_part, float* __restrict__ stats_ws)
{
    const int bid = blockIdx.x;
    // decode: bid = (((e>>1)*8 + (b>>2))*2 + dh)*8 + ((b&3)*2 + (e&1))
    const int lo   = bid & 7;         // XCD id: (b&3)*2 + (e&1)
    const int hi   = bid >> 3;
    const int dh   = hi & 1;
    const int t2   = hi >> 1;
    const int b    = ((t2 & 7) << 2) | (lo >> 1);
    const int e    = ((t2 >> 3) << 1) | (lo & 1);
    const int tid  = threadIdx.x;
    const int t0   = 2 * dh;          // first d-tile of this block's half

    __shared__ float wtT[DT][DMODEL + 1];          // 65.8 KB transposed tile
    __shared__ float xn[LSEQ];
    __shared__ float xp_s[NP * DMODEL];
    __shared__ float red[8];
    __shared__ float lg[32];
    __shared__ float g_s[NP];
    __shared__ float mean_s, rstd_s;

    // ---- issue series loads FIRST (long latency), then this half's tile-0
    float v[4];
    #pragma unroll
    for (int i = 0; i < 4; ++i)
        v[i] = x[(size_t)(b * LSEQ + tid + 256 * i) * CCH + 2];

    // W tile mapping: c4 = float4 chunk of d, hb+16i = h row (coalesced).
    const int c4 = tid & 15;
    const int hb = tid >> 4;
    const float* wsrc = W_experts + ((size_t)e << 16);
    float4 wreg[16];
    #pragma unroll
    for (int i = 0; i < 16; ++i)
        wreg[i] = *(const float4*)(wsrc + (size_t)(hb + 16 * i) * DMODEL
                                   + t0 * DT + 4 * c4);

    // ---- stats over the 1024-length series
    {
        float s = 0.f, sq = 0.f;
        #pragma unroll
        for (int i = 0; i < 4; ++i) { s += v[i]; sq += v[i] * v[i]; }
        #pragma unroll
        for (int off = 32; off > 0; off >>= 1) {
            s  += __shfl_down(s,  off);
            sq += __shfl_down(sq, off);
        }
        const int wave = tid >> 6;
        if ((tid & 63) == 0) { red[wave * 2] = s; red[wave * 2 + 1] = sq; }
        __syncthreads();
        if (tid == 0) {
            const float S = red[0] + red[2] + red[4] + red[6];
            const float Q = red[1] + red[3] + red[5] + red[7];
            const float mean = S * (1.0f / LSEQ);
            const float var  = Q * (1.0f / LSEQ) - mean * mean;
            const float stdv = sqrtf(var + 1e-5f);
            mean_s = mean;
            rstd_s = 1.0f / stdv;
            if (e == 0 && dh == 0) {      // one writer per batch
                stats_ws[b * 2]     = mean;
                stats_ws[b * 2 + 1] = stdv;
            }
        }
        __syncthreads();
        const float mean = mean_s, rstd = rstd_s;
        #pragma unroll
        for (int i = 0; i < 4; ++i)
            xn[tid + 256 * i] = (v[i] - mean) * rstd;
        __syncthreads();
    }

    // ---- patch projection: xp[p][h], thread h
    {
        const int h = tid;
        float wrow[16];
        #pragma unroll
        for (int j = 0; j < 16; ++j) wrow[j] = W_proj[h * 16 + j];
        const float bp = b_proj[h];
        #pragma unroll
        for (int p = 0; p < NP; ++p) {
            float acc = bp;
            #pragma unroll
            for (int j = 0; j < 16; ++j) acc += xn[p * 16 + j] * wrow[j];
            xp_s[p * DMODEL + h] = acc;
        }
    }
    __syncthreads();

    // ---- router logits, parallel: 8 lanes per (p,e') pair
    {
        const int pe = tid >> 3;
        const int sl = tid & 7;
        const int p  = pe >> 3;
        const int er = pe & 7;
        float acc = 0.f;
        #pragma unroll 8
        for (int j = 0; j < 32; ++j) {
            const int hh = sl + 8 * j;
            acc += xp_s[p * DMODEL + hh] * W_router[er * DMODEL + hh];
        }
        acc += __shfl_xor(acc, 4);
        acc += __shfl_xor(acc, 2);
        acc += __shfl_xor(acc, 1);
        if (sl == 0) lg[pe] = acc + b_router[er];
    }
    __syncthreads();

    // ---- softmax over 8 experts; keep only this block's gate g[p]
    if (tid < NP) {
        const int p = tid;
        float m = -1e30f;
        #pragma unroll
        for (int k = 0; k < NEXP; ++k) m = fmaxf(m, lg[p * 8 + k]);
        float ex[NEXP];
        float sum = 0.f;
        #pragma unroll
        for (int k = 0; k < NEXP; ++k) { ex[k] = expf(lg[p * 8 + k] - m); sum += ex[k]; }
        g_s[p] = ex[e] / sum;
    }
    // g_s visibility covered by the tile-loop barriers below

    // ---- expert matvec: 2 d-tiles (this half), LDS transpose, prefetch
    float acc0 = 0.f, acc1 = 0.f, acc2 = 0.f, acc3 = 0.f;
    for (int it = 0; it < 2; ++it) {
        __syncthreads();   // protect wtT from overwrite while prior reads run
        #pragma unroll
        for (int i = 0; i < 16; ++i) {
            const int h = hb + 16 * i;
            wtT[4 * c4 + 0][h] = wreg[i].x;
            wtT[4 * c4 + 1][h] = wreg[i].y;
            wtT[4 * c4 + 2][h] = wreg[i].z;
            wtT[4 * c4 + 3][h] = wreg[i].w;
        }
        __syncthreads();
        if (it == 0) {
            #pragma unroll
            for (int i = 0; i < 16; ++i)
                wreg[i] = *(const float4*)(wsrc + (size_t)(hb + 16 * i) * DMODEL
                                           + (t0 + 1) * DT + 4 * c4);
        }
        const float* xpp = xp_s + (t0 + it) * DT;
        #pragma unroll 8
        for (int c = 0; c < DT; ++c) {
            const float wv = wtT[c][tid];
            acc0 += xpp[c]       * wv;
            acc1 += xpp[256 + c] * wv;
            acc2 += xpp[512 + c] * wv;
            acc3 += xpp[768 + c] * wv;
        }
    }

    // ---- gated write of this (e,dh) partial (coalesced, disjoint)
    const float bias = (dh == 0) ? b_experts[(e << 8) + tid] : 0.f;
    const int part = (e << 1) | dh;
    const size_t base = ((size_t)(part * NB + b) << 10) + tid;
    flat_part[base]         = g_s[0] * (acc0 + bias);
    flat_part[base + 256]   = g_s[1] * (acc1 + bias);
    flat_part[base + 512]   = g_s[2] * (acc2 + bias);
    flat_part[base + 768]   = g_s[3] * (acc3 + bias);
}

// ---------------------------------------------------------------------------
// Kernel B: sum 16 partials, un-normalize, head matvec.  (R9 verbatim)
// grid = 256: bid -> (b = bid>>3, kq = bid&7); block = 256 (4 waves).
// ---------------------------------------------------------------------------
__global__ __launch_bounds__(256) void k_head(
    const float* __restrict__ flat_part, const float* __restrict__ stats_ws,
    const float* __restrict__ W_head, const float* __restrict__ b_head,
    float* __restrict__ out)
{
    const int b   = blockIdx.x >> 3;
    const int kq  = blockIdx.x & 7;
    const int tid = threadIdx.x;
    __shared__ float4 f4s[DMODEL];   // 1024 floats

    const float mean = stats_ws[b * 2];
    const float stdv = stats_ws[b * 2 + 1];

    // stage: f[l] = (sum_part part[i][b][l]) * std + mean  (fixed i-order)
    {
        float4 acc = make_float4(0.f, 0.f, 0.f, 0.f);
        #pragma unroll
        for (int i = 0; i < NPART; ++i) {
            const float4 t =
                ((const float4*)(flat_part + (((size_t)i * NB + b) << 10)))[tid];
            acc.x += t.x; acc.y += t.y; acc.z += t.z; acc.w += t.w;
        }
        acc.x = acc.x * stdv + mean;
        acc.y = acc.y * stdv + mean;
        acc.z = acc.z * stdv + mean;
        acc.w = acc.w * stdv + mean;
        f4s[tid] = acc;
    }
    __syncthreads();

    const int lane = tid & 63;
    const int w    = tid >> 6;
    float4 fr[4];
    #pragma unroll
    for (int c = 0; c < 4; ++c) fr[c] = f4s[lane + 64 * c];

    #pragma unroll
    for (int i = 0; i < 3; ++i) {
        const int k = kq * 12 + w + 4 * i;
        const float4* wr = (const float4*)(W_head + (size_t)k * LSEQ);
        float a = 0.f;
        #pragma unroll
        for (int c = 0; c < 4; ++c) {
            const float4 t = wr[lane + 64 * c];
            a += t.x * fr[c].x + t.y * fr[c].y + t.z * fr[c].z + t.w * fr[c].w;
        }
        #pragma unroll
        for (int off = 32; off > 0; off >>= 1)
            a += __shfl_xor(a, off);
        if (lane == 0)
            out[(size_t)b * PRED + k] = b_head[k] + a;
    }
}

// ---------------------------------------------------------------------------
extern "C" void kernel_launch(void* const* d_in, const int* in_sizes, int n_in,
                              void* d_out, int out_size, void* d_ws, size_t ws_size,
                              hipStream_t stream)
{
    const float* x         = (const float*)d_in[0];
    const float* W_proj    = (const float*)d_in[4];
    const float* b_proj    = (const float*)d_in[5];
    const float* W_router  = (const float*)d_in[6];
    const float* b_router  = (const float*)d_in[7];
    const float* W_experts = (const float*)d_in[8];
    const float* b_experts = (const float*)d_in[9];
    const float* W_head    = (const float*)d_in[10];
    const float* b_head    = (const float*)d_in[11];
    float* out = (float*)d_out;
    float* ws  = (float*)d_ws;

    float* stats_ws  = ws;
    float* flat_part = ws + STATS_FLOATS;   // 16 x NB x LSEQ floats

    k_fused<<<512, 256, 0, stream>>>(x, W_proj, b_proj, W_router, b_router,
                                     W_experts, b_experts, flat_part, stats_ws);
    k_head<<<256, 256, 0, stream>>>(flat_part, stats_ws, W_head, b_head, out);
}

// Round 6
// 96.596 us; speedup vs baseline: 1.6510x; 1.0001x over previous
//
#include <hip/hip_runtime.h>
#include <math.h>

// ---------------------------------------------------------------------------
// Problem: B=32, L=1024, C=34, PATCH=16, d=256, E=8, pred=96.
// Algebraic reductions (verified R1-R7):
//   * final [:, :, :1] slice -> only channel n=0 per batch (series x[b,:,2])
//   * flat[:, :1024] truncation -> only patches p=0..3 contribute
//
// LEDGER: R13 (d-split grid 512 + XCD grouping) = 96.6us BEST.
//   R10 fused 2-kernel = 98.8.  R11 coop = 159.5 (REVERTED).
//   R12 block-1024 = 113.9 (REVERTED).
//   Window decomposition: 2 harness re-poison fills x ~40.5us (82-83% HBM
//   peak = their own roofline, untouchable) + ~5us kernels + ~9us dispatch
//   overhead (4 dispatches).  Controllable = kernel serial chains only.
//
// R14 = R13 + serial-chain trims (no restructure):
//   * stats finished redundantly per-thread from red[8] after ONE barrier
//     (kills a barrier + mean_s/rstd_s LDS round-trip through tid0);
//     identical float order -> bit-identical output.
//   * xn shrunk 1024->64 floats (proj only reads l=0..63; thread tid<64
//     writes its v[0]); LDS 74->70KB, occupancy unchanged 2 blk/CU.
//   * W_proj row loads 16 scalar -> 4x float4 (same FMA order).
//   * k_head: flat_part loads issued before stats scalars; bias hoisted.
// Decision rule (pre-committed): dur >= 96.0 -> declare roofline.
// ---------------------------------------------------------------------------

#define NB 32
#define LSEQ 1024
#define CCH 34
#define NP 4
#define DMODEL 256
#define NEXP 8
#define PRED 96
#define DT 64                                   // d-tile width
#define NPART (2 * NEXP)                        // 16 partials (e, dh)

#define STATS_FLOATS (NB * 2)                   // 64

// ---------------------------------------------------------------------------
// Kernel A: fused stats + patch-proj + router + half-d expert matvec.
// grid = 512: bid -> (b, e, dh) via XCD-aware encode (see launch);
// block = 256.  LDS ~70 KB -> 2 blocks/CU (2 waves/SIMD).
// ---------------------------------------------------------------------------
__global__ __launch_bounds__(256, 2) void k_fused(
    const float* __restrict__ x,
    const float* __restrict__ W_proj, const float* __restrict__ b_proj,
    const float* __restrict__ W_router, const float* __restrict__ b_router,
    const float* __restrict__ W_experts, const float* __restrict__ b_experts,
    float* __restrict__ flat_part, float* __restrict__ stats_ws)
{
    const int bid = blockIdx.x;
    // decode: bid = (((e>>1)*8 + (b>>2))*2 + dh)*8 + ((b&3)*2 + (e&1))
    const int lo   = bid & 7;         // XCD id: (b&3)*2 + (e&1)
    const int hi   = bid >> 3;
    const int dh   = hi & 1;
    const int t2   = hi >> 1;
    const int b    = ((t2 & 7) << 2) | (lo >> 1);
    const int e    = ((t2 >> 3) << 1) | (lo & 1);
    const int tid  = threadIdx.x;
    const int t0   = 2 * dh;          // first d-tile of this block's half

    __shared__ float wtT[DT][DMODEL + 1];          // 65.8 KB transposed tile
    __shared__ float xn[64];                        // only l=0..63 used
    __shared__ float xp_s[NP * DMODEL];
    __shared__ float red[8];
    __shared__ float lg[32];
    __shared__ float g_s[NP];

    // ---- issue series loads FIRST (long latency), then this half's tile-0
    float v[4];
    #pragma unroll
    for (int i = 0; i < 4; ++i)
        v[i] = x[(size_t)(b * LSEQ + tid + 256 * i) * CCH + 2];

    // W tile mapping: c4 = float4 chunk of d, hb+16i = h row (coalesced).
    const int c4 = tid & 15;
    const int hb = tid >> 4;
    const float* wsrc = W_experts + ((size_t)e << 16);
    float4 wreg[16];
    #pragma unroll
    for (int i = 0; i < 16; ++i)
        wreg[i] = *(const float4*)(wsrc + (size_t)(hb + 16 * i) * DMODEL
                                   + t0 * DT + 4 * c4);

    // hoist small scalars into the latency shadow
    const float bias = (dh == 0) ? b_experts[(e << 8) + tid] : 0.f;

    // ---- stats over the 1024-length series (one barrier; redundant finish)
    {
        float s = 0.f, sq = 0.f;
        #pragma unroll
        for (int i = 0; i < 4; ++i) { s += v[i]; sq += v[i] * v[i]; }
        #pragma unroll
        for (int off = 32; off > 0; off >>= 1) {
            s  += __shfl_down(s,  off);
            sq += __shfl_down(sq, off);
        }
        const int wave = tid >> 6;
        if ((tid & 63) == 0) { red[wave * 2] = s; red[wave * 2 + 1] = sq; }
        __syncthreads();
        // every thread finishes the reduction from LDS broadcasts
        // (identical float order to R13: red[0]+red[2]+red[4]+red[6])
        const float S = red[0] + red[2] + red[4] + red[6];
        const float Q = red[1] + red[3] + red[5] + red[7];
        const float mean = S * (1.0f / LSEQ);
        const float var  = Q * (1.0f / LSEQ) - mean * mean;
        const float stdv = sqrtf(var + 1e-5f);
        const float rstd = 1.0f / stdv;
        if (tid == 0 && e == 0 && dh == 0) {      // one writer per batch
            stats_ws[b * 2]     = mean;
            stats_ws[b * 2 + 1] = stdv;
        }
        if (tid < 64) xn[tid] = (v[0] - mean) * rstd;   // l = tid < 64 only
        __syncthreads();
    }

    // ---- patch projection: xp[p][h], thread h (only l=0..63 feed patches)
    {
        const int h = tid;
        const float4* wp4 = (const float4*)(W_proj + h * 16);
        float wrow[16];
        #pragma unroll
        for (int q = 0; q < 4; ++q) {
            const float4 w4 = wp4[q];
            wrow[4 * q + 0] = w4.x; wrow[4 * q + 1] = w4.y;
            wrow[4 * q + 2] = w4.z; wrow[4 * q + 3] = w4.w;
        }
        const float bp = b_proj[h];
        #pragma unroll
        for (int p = 0; p < NP; ++p) {
            float acc = bp;
            #pragma unroll
            for (int j = 0; j < 16; ++j) acc += xn[p * 16 + j] * wrow[j];
            xp_s[p * DMODEL + h] = acc;
        }
    }
    __syncthreads();

    // ---- router logits, parallel: 8 lanes per (p,e') pair
    {
        const int pe = tid >> 3;
        const int sl = tid & 7;
        const int p  = pe >> 3;
        const int er = pe & 7;
        float acc = 0.f;
        #pragma unroll 8
        for (int j = 0; j < 32; ++j) {
            const int hh = sl + 8 * j;
            acc += xp_s[p * DMODEL + hh] * W_router[er * DMODEL + hh];
        }
        acc += __shfl_xor(acc, 4);
        acc += __shfl_xor(acc, 2);
        acc += __shfl_xor(acc, 1);
        if (sl == 0) lg[pe] = acc + b_router[er];
    }
    __syncthreads();

    // ---- softmax over 8 experts; keep only this block's gate g[p]
    if (tid < NP) {
        const int p = tid;
        float m = -1e30f;
        #pragma unroll
        for (int k = 0; k < NEXP; ++k) m = fmaxf(m, lg[p * 8 + k]);
        float ex[NEXP];
        float sum = 0.f;
        #pragma unroll
        for (int k = 0; k < NEXP; ++k) { ex[k] = expf(lg[p * 8 + k] - m); sum += ex[k]; }
        g_s[p] = ex[e] / sum;
    }
    // g_s visibility covered by the tile-loop barriers below

    // ---- expert matvec: 2 d-tiles (this half), LDS transpose, prefetch
    float acc0 = 0.f, acc1 = 0.f, acc2 = 0.f, acc3 = 0.f;
    for (int it = 0; it < 2; ++it) {
        __syncthreads();   // protect wtT from overwrite while prior reads run
        #pragma unroll
        for (int i = 0; i < 16; ++i) {
            const int h = hb + 16 * i;
            wtT[4 * c4 + 0][h] = wreg[i].x;
            wtT[4 * c4 + 1][h] = wreg[i].y;
            wtT[4 * c4 + 2][h] = wreg[i].z;
            wtT[4 * c4 + 3][h] = wreg[i].w;
        }
        __syncthreads();
        if (it == 0) {
            #pragma unroll
            for (int i = 0; i < 16; ++i)
                wreg[i] = *(const float4*)(wsrc + (size_t)(hb + 16 * i) * DMODEL
                                           + (t0 + 1) * DT + 4 * c4);
        }
        const float* xpp = xp_s + (t0 + it) * DT;
        #pragma unroll 8
        for (int c = 0; c < DT; ++c) {
            const float wv = wtT[c][tid];
            acc0 += xpp[c]       * wv;
            acc1 += xpp[256 + c] * wv;
            acc2 += xpp[512 + c] * wv;
            acc3 += xpp[768 + c] * wv;
        }
    }

    // ---- gated write of this (e,dh) partial (coalesced, disjoint)
    const int part = (e << 1) | dh;
    const size_t base = ((size_t)(part * NB + b) << 10) + tid;
    flat_part[base]         = g_s[0] * (acc0 + bias);
    flat_part[base + 256]   = g_s[1] * (acc1 + bias);
    flat_part[base + 512]   = g_s[2] * (acc2 + bias);
    flat_part[base + 768]   = g_s[3] * (acc3 + bias);
}

// ---------------------------------------------------------------------------
// Kernel B: sum 16 partials, un-normalize, head matvec.
// grid = 256: bid -> (b = bid>>3, kq = bid&7); block = 256 (4 waves).
// ---------------------------------------------------------------------------
__global__ __launch_bounds__(256) void k_head(
    const float* __restrict__ flat_part, const float* __restrict__ stats_ws,
    const float* __restrict__ W_head, const float* __restrict__ b_head,
    float* __restrict__ out)
{
    const int b   = blockIdx.x >> 3;
    const int kq  = blockIdx.x & 7;
    const int tid = threadIdx.x;
    __shared__ float4 f4s[DMODEL];   // 1024 floats

    // stage: issue all 16 partial loads first (latency overlap), then stats
    {
        float4 acc = make_float4(0.f, 0.f, 0.f, 0.f);
        #pragma unroll
        for (int i = 0; i < NPART; ++i) {
            const float4 t =
                ((const float4*)(flat_part + (((size_t)i * NB + b) << 10)))[tid];
            acc.x += t.x; acc.y += t.y; acc.z += t.z; acc.w += t.w;
        }
        const float mean = stats_ws[b * 2];
        const float stdv = stats_ws[b * 2 + 1];
        acc.x = acc.x * stdv + mean;
        acc.y = acc.y * stdv + mean;
        acc.z = acc.z * stdv + mean;
        acc.w = acc.w * stdv + mean;
        f4s[tid] = acc;
    }
    __syncthreads();

    const int lane = tid & 63;
    const int w    = tid >> 6;
    float4 fr[4];
    #pragma unroll
    for (int c = 0; c < 4; ++c) fr[c] = f4s[lane + 64 * c];

    #pragma unroll
    for (int i = 0; i < 3; ++i) {
        const int k = kq * 12 + w + 4 * i;
        const float4* wr = (const float4*)(W_head + (size_t)k * LSEQ);
        float a = 0.f;
        #pragma unroll
        for (int c = 0; c < 4; ++c) {
            const float4 t = wr[lane + 64 * c];
            a += t.x * fr[c].x + t.y * fr[c].y + t.z * fr[c].z + t.w * fr[c].w;
        }
        #pragma unroll
        for (int off = 32; off > 0; off >>= 1)
            a += __shfl_xor(a, off);
        if (lane == 0)
            out[(size_t)b * PRED + k] = b_head[k] + a;
    }
}

// ---------------------------------------------------------------------------
extern "C" void kernel_launch(void* const* d_in, const int* in_sizes, int n_in,
                              void* d_out, int out_size, void* d_ws, size_t ws_size,
                              hipStream_t stream)
{
    const float* x         = (const float*)d_in[0];
    const float* W_proj    = (const float*)d_in[4];
    const float* b_proj    = (const float*)d_in[5];
    const float* W_router  = (const float*)d_in[6];
    const float* b_router  = (const float*)d_in[7];
    const float* W_experts = (const float*)d_in[8];
    const float* b_experts = (const float*)d_in[9];
    const float* W_head    = (const float*)d_in[10];
    const float* b_head    = (const float*)d_in[11];
    float* out = (float*)d_out;
    float* ws  = (float*)d_ws;

    float* stats_ws  = ws;
    float* flat_part = ws + STATS_FLOATS;   // 16 x NB x LSEQ floats

    k_fused<<<512, 256, 0, stream>>>(x, W_proj, b_proj, W_router, b_router,
                                     W_experts, b_experts, flat_part, stats_ws);
    k_head<<<256, 256, 0, stream>>>(flat_part, stats_ws, W_head, b_head, out);
}